// Round 1
// baseline (1073.845 us; speedup 1.0000x reference)
//
#include <hip/hip_runtime.h>
#include <cmath>

// VanillaRNN: B=256, T=128, D=1, H=2048, C=10
// R12: R11 (512-thr blocks, 2 waves/SIMD, packed sc1 h-exchange, W hi+lo
// fp16 in regs, 8-way K-split, per-producer data-ready flags) with the
// flag signal HARDENED: instead of one posted sc1 store, the producer's
// tid0 issues TWO CHAINED atomic fetch_adds on the flag line (the second's
// operand depends on the first's returned value, forcing a full MALL round
// trip between them; RMWs commit at the MALL). Consumers poll v >= 2.
// This gives the same release-path slack as the deterministic R10 barrier
// (R11's plain store could become visible while data write-through was
// still in flight -> occasional stale fragments -> tripwire divergence).
// Protocol recap: wave w consumes only producers C' in [8w,8w+8); it polls
// exactly those 8 flags (slot t-1) and starts its K-loop immediately.
// Overwrite safety is transitive through the pre-reduction __syncthreads.

#define B_ 256
#define T_ 128
#define H_ 2048
#define C_ 10

typedef _Float16 half_t;
typedef _Float16 half8 __attribute__((ext_vector_type(8)));
typedef _Float16 half4v __attribute__((ext_vector_type(4)));
typedef float floatx4 __attribute__((ext_vector_type(4)));
typedef unsigned long long u64;
typedef unsigned long long u64x2 __attribute__((ext_vector_type(2)));

// flag array: dword index  t*(4*64*32) + (g*64 + C)*32   (one 128B line per
// flag). t in [0,127), g in [0,4), C = producer block-in-group [0,64).
#define FLAG_DWORDS (128 * 4 * 64 * 32)   // 4 MB

__device__ __forceinline__ float fast_tanh(float v) {
    return 1.0f - 2.0f / (__expf(2.0f * v) + 1.0f);
}

// hardened release: two chained RMWs (2nd operand depends on 1st's result)
__device__ __forceinline__ void signal_flag(unsigned* fl) {
    unsigned o1 = __hip_atomic_fetch_add(fl, 1u, __ATOMIC_RELAXED,
                                         __HIP_MEMORY_SCOPE_AGENT);
    __hip_atomic_fetch_add(fl, 1u + (o1 >> 31), __ATOMIC_RELAXED,
                           __HIP_MEMORY_SCOPE_AGENT);
}

// ---- persistent RNN kernel: 256 blocks x 512 thr (8 waves, 2/SIMD) ----
__global__ void __launch_bounds__(512, 2) rnn_persist(
    const float* __restrict__ x,   // [B_,T_]
    const float* __restrict__ U,   // [H_]
    const float* __restrict__ W,   // [H_,H_] fp32
    const float* __restrict__ bh,  // [H_]
    half_t* __restrict__ hP0,      // packed state buf 0 (1 MB)
    half_t* __restrict__ hP1,      // packed state buf 1 (1 MB)
    float* __restrict__ hf32,      // d_out h_last region (row-major fp32)
    unsigned* __restrict__ flags)
{
    const int tid  = threadIdx.x;
    const int wave = tid >> 6, lane = tid & 63;
    const int quad = lane >> 4, lq = lane & 15;
    const int id   = blockIdx.x;
    const int grp  = id & 7;
    const int g    = grp >> 1, p = grp & 1;
    const int m0   = g * 64;                      // m-group g owns rows m0..m0+63
    const int C    = (id >> 3) * 2 + p;           // n-chunk 0..63 (= block-in-group)
    const int n0   = C * 32;

    // ---- one-time: W frags for this wave's K-range -> regs (hi+lo) ----
    half8 Bhi[8][2], Blo[8][2];
#pragma unroll
    for (int c = 0; c < 8; ++c) {
#pragma unroll
        for (int nt = 0; nt < 2; ++nt) {
            const int gn = n0 + nt * 16 + lq;
            const int k0 = (wave * 8 + c) * 32 + quad * 8;
            const float4 w0 = *(const float4*)&W[(size_t)gn * H_ + k0];
            const float4 w1 = *(const float4*)&W[(size_t)gn * H_ + k0 + 4];
            const float wv[8] = {w0.x, w0.y, w0.z, w0.w, w1.x, w1.y, w1.z, w1.w};
            half8 hi, lo;
#pragma unroll
            for (int j = 0; j < 8; ++j) {
                hi[j] = (half_t)wv[j];
                lo[j] = (half_t)(wv[j] - (float)hi[j]);
            }
            Bhi[c][nt] = hi;
            Blo[c][nt] = lo;
        }
    }

    // epilogue-owner role: wave w handles (msub, ntO)
    const int msub = wave & 3, ntO = wave >> 2;
    const float uvO = U[n0 + ntO * 16 + lq];
    const float bvO = bh[n0 + ntO * 16 + lq];

    __shared__ floatx4 red[4][8][2][64];          // 8-way k-split, 64 KB
    __shared__ float Sm[64][33];                  // epilogue transpose, 8.4 KB
    __shared__ float xs[T_][64];                  // x slab transposed, 32 KB

    for (int i = tid; i < 64 * T_; i += 512) {    // one-time x staging
        const int r = i & 63, tt = i >> 6;
        xs[tt][r] = x[(size_t)(m0 + r) * T_ + tt];
    }
    __syncthreads();

    // producer mapping (R10-validated): 512 thr x 1 u64 (4 halfs)
    const int prow = (tid >> 7) * 16 + ((tid >> 1) & 15);   // local row 0..63
    const int pcol = ((tid >> 5) & 3) * 8 + (tid & 1) * 4;  // local col base
    const size_t slab = (size_t)g * 32768;                  // u64 units
    const size_t pdst = slab + (size_t)C * 512 + tid;
    const size_t cbase = slab + (size_t)wave * 4096 + (size_t)lane * 2;

    // flag addresses
    unsigned* myflag_base = flags + ((size_t)g * 64 + C) * 32;     // + t*4*64*32
    const unsigned* pollp = flags + ((size_t)g * 64 + wave * 8 + (lane & 7)) * 32;

    // ---- step 0: h1 = tanh(x*U + bh) -> packed hP1, signal slot 0 ----
    {
        const float xb = xs[0][prow];
        half4v hv;
#pragma unroll
        for (int j = 0; j < 4; ++j) {
            const int n = n0 + pcol + j;
            hv[j] = (half_t)fast_tanh(xb * U[n] + bh[n]);
        }
        __hip_atomic_store((u64*)hP1 + pdst, __builtin_bit_cast(u64, hv),
                           __ATOMIC_RELAXED, __HIP_MEMORY_SCOPE_AGENT);
    }
    __syncthreads();                              // drain all lanes' publishes
    if (tid == 0) signal_flag(myflag_base);

    // ---- steps t = 1..127 ----
    for (int t = 1; t < T_; ++t) {
        const half_t* hin = (t & 1) ? hP1 : hP0;  // h_t (packed)
        half_t* hout      = (t & 1) ? hP0 : hP1;  // h_{t+1} (packed)
        const u64* pw = (const u64*)hin + cbase;

        // wave-level poll: my 8 producers for slot t-1 (hardened: v >= 2)
        {
            const unsigned* fp = pollp + (size_t)(t - 1) * (4 * 64 * 32);
            while (true) {
                const unsigned v = __hip_atomic_load(fp, __ATOMIC_RELAXED,
                                                     __HIP_MEMORY_SCOPE_AGENT);
                if (__all(v >= 2u)) break;
                __builtin_amdgcn_s_sleep(1);
            }
            asm volatile("" ::: "memory");        // no load hoisting above poll
        }

        floatx4 acc[4][2] = {};

        u64 rl[8], rh[8];                         // ring-8 of 16B frags
        auto issue = [&](int f) {
            const u64* q = pw + (size_t)((f >> 2) * 512 + (f & 3) * 128);
            rl[f & 7] = __hip_atomic_load(q, __ATOMIC_RELAXED,
                                          __HIP_MEMORY_SCOPE_AGENT);
            rh[f & 7] = __hip_atomic_load(q + 1, __ATOMIC_RELAXED,
                                          __HIP_MEMORY_SCOPE_AGENT);
        };
#pragma unroll
        for (int f = 0; f < 8; ++f) issue(f);
#pragma unroll
        for (int f = 0; f < 32; ++f) {            // c' = f>>2 in [0,8), mt = f&3
            const int c = f >> 2, mt = f & 3;
            u64x2 bits; bits.x = rl[f & 7]; bits.y = rh[f & 7];
            const half8 av = __builtin_bit_cast(half8, bits);
            if (f + 8 < 32) issue(f + 8);
            acc[mt][0] = __builtin_amdgcn_mfma_f32_16x16x32_f16(av, Bhi[c][0], acc[mt][0], 0, 0, 0);
            acc[mt][1] = __builtin_amdgcn_mfma_f32_16x16x32_f16(av, Bhi[c][1], acc[mt][1], 0, 0, 0);
            acc[mt][0] = __builtin_amdgcn_mfma_f32_16x16x32_f16(av, Blo[c][0], acc[mt][0], 0, 0, 0);
            acc[mt][1] = __builtin_amdgcn_mfma_f32_16x16x32_f16(av, Blo[c][1], acc[mt][1], 0, 0, 0);
        }

        // ---- 8-way K-split reduction ----
#pragma unroll
        for (int mt = 0; mt < 4; ++mt)
#pragma unroll
            for (int nt = 0; nt < 2; ++nt)
                red[mt][wave][nt][lane] = acc[mt][nt];
        __syncthreads();

        // owner wave: sum 8 partials, +x*U+bh, tanh -> Sm
        {
            float xr[4];
#pragma unroll
            for (int r = 0; r < 4; ++r) xr[r] = xs[t][msub * 16 + quad * 4 + r];
            floatx4 s = red[msub][0][ntO][lane];
#pragma unroll
            for (int ww = 1; ww < 8; ++ww) s += red[msub][ww][ntO][lane];
#pragma unroll
            for (int r = 0; r < 4; ++r) {
                const float pre = s[r] + xr[r] * uvO + bvO;
                Sm[msub * 16 + quad * 4 + r][ntO * 16 + lq] = fast_tanh(pre);
            }
        }
        __syncthreads();

        // publish: 1 u64 (4 halfs) per thread into the packed slab
        {
            float fv[4];
#pragma unroll
            for (int j = 0; j < 4; ++j) fv[j] = Sm[prow][pcol + j];
            half4v hv;
#pragma unroll
            for (int j = 0; j < 4; ++j) hv[j] = (half_t)fv[j];
            __hip_atomic_store((u64*)hout + pdst, __builtin_bit_cast(u64, hv),
                               __ATOMIC_RELAXED, __HIP_MEMORY_SCOPE_AGENT);
            if (t == T_ - 1) {  // final h_128 also to d_out, row-major fp32
                float* fd = hf32 + (size_t)(m0 + prow) * H_ + n0 + pcol;
                *(float4*)fd = make_float4(fv[0], fv[1], fv[2], fv[3]);
            }
        }
        if (t < T_ - 1) {
            __syncthreads();                      // drain publishes block-wide
            if (tid == 0)
                signal_flag(myflag_base + (size_t)t * (4 * 64 * 32));
        }
    }
}

// ---- output projection: out[b,c] = h[b,:] . V[c,:] + bp[c] ----
__global__ __launch_bounds__(256) void rnn_out(
    const float* __restrict__ h, const float* __restrict__ V,
    const float* __restrict__ bp, float* __restrict__ outp) {
    const int b = blockIdx.x;
    const int tid = threadIdx.x;
    float acc[C_] = {};
    for (int k = tid; k < H_; k += 256) {
        const float hv = h[(size_t)b * H_ + k];
#pragma unroll
        for (int c = 0; c < C_; ++c) acc[c] += hv * V[(size_t)c * H_ + k];
    }
#pragma unroll
    for (int c = 0; c < C_; ++c)
#pragma unroll
        for (int off = 32; off > 0; off >>= 1)
            acc[c] += __shfl_down(acc[c], off, 64);
    __shared__ float partial[4][C_];
    const int wave = tid >> 6, lane = tid & 63;
    if (lane == 0)
#pragma unroll
        for (int c = 0; c < C_; ++c) partial[wave][c] = acc[c];
    __syncthreads();
    if (tid < C_)
        outp[b * C_ + tid] = partial[0][tid] + partial[1][tid]
                           + partial[2][tid] + partial[3][tid] + bp[tid];
}

extern "C" void kernel_launch(void* const* d_in, const int* in_sizes, int n_in,
                              void* d_out, int out_size, void* d_ws, size_t ws_size,
                              hipStream_t stream) {
    const float* x  = (const float*)d_in[0];
    const float* U  = (const float*)d_in[1];
    const float* W  = (const float*)d_in[2];
    const float* V  = (const float*)d_in[3];
    const float* bh = (const float*)d_in[4];
    const float* bp = (const float*)d_in[5];

    float* out_h = (float*)d_out;                 // [B_*H_] fp32 h_last
    float* outp  = out_h + (size_t)B_ * H_;       // [B_*C_]

    half_t* hP0 = (half_t*)d_ws;                                   // 1 MB packed
    half_t* hP1 = hP0 + (size_t)B_ * H_;                           // 1 MB packed
    unsigned* flags = (unsigned*)((char*)d_ws + 2u * 1024 * 1024); // 4 MB

    hipMemsetAsync(flags, 0, FLAG_DWORDS * sizeof(unsigned), stream);

    rnn_persist<<<dim3(256), dim3(512), 0, stream>>>(
        x, U, W, bh, hP0, hP1, out_h, flags);

    rnn_out<<<dim3(B_), dim3(256), 0, stream>>>(out_h, V, bp, outp);
}

// Round 2
// 694.624 us; speedup vs baseline: 1.5459x; 1.5459x over previous
//
#include <hip/hip_runtime.h>
#include <cmath>

// VanillaRNN: B=256, T=128, D=1, H=2048, C=10
// R13: structural re-shard. 8 groups (g=id&7, rows m0=g*32..+32) x 32 blocks
// (C=id>>3, cols n0=C*64..+64). W held as SINGLE fp16 in regs (128 VGPR/thr,
// no hi/lo split) -> each block owns 64 cols x 2048 K. This halves:
//   - the per-step h broadcast (group slab 128 KB read by 32 blocks
//     -> 32 MB/step chip-wide, was 64 MB),
//   - the MFMA work (64 mfma/wave/step, was 128 hi+lo),
//   - the poll set (4 producers/wave, was 8).
// Groups are 32 blocks = one XCD under id%8 round-robin (perf-only bonus;
// correctness never depends on placement). The validated R12 sync protocol
// is UNCHANGED: packed u64 publishes, __syncthreads drain, tid0 signals via
// TWO CHAINED agent RMWs on a private 128B flag line, consumers poll v>=2.
// Overwrite safety transitive as before: all 32 group producers' t-1 flags
// are collectively polled (8 waves x 4) before any wave passes the
// pre-reduction __syncthreads, so publishing t (overwrites t-2) is safe.

#define B_ 256
#define T_ 128
#define H_ 2048
#define C_ 10

typedef _Float16 half_t;
typedef _Float16 half8 __attribute__((ext_vector_type(8)));
typedef _Float16 half4v __attribute__((ext_vector_type(4)));
typedef float floatx4 __attribute__((ext_vector_type(4)));
typedef unsigned long long u64;
typedef unsigned long long u64x2 __attribute__((ext_vector_type(2)));

// flag array: dword index  t*(8*32*32) + (g*32 + C)*32  (one 128B line per
// flag). t in [0,127), g in [0,8), C = producer block-in-group [0,32).
#define FLAG_DWORDS (128 * 8 * 32 * 32)   // 4 MB

__device__ __forceinline__ float fast_tanh(float v) {
    return 1.0f - 2.0f / (__expf(2.0f * v) + 1.0f);
}

// hardened release: two chained RMWs (2nd operand depends on 1st's result)
__device__ __forceinline__ void signal_flag(unsigned* fl) {
    unsigned o1 = __hip_atomic_fetch_add(fl, 1u, __ATOMIC_RELAXED,
                                         __HIP_MEMORY_SCOPE_AGENT);
    __hip_atomic_fetch_add(fl, 1u + (o1 >> 31), __ATOMIC_RELAXED,
                           __HIP_MEMORY_SCOPE_AGENT);
}

// ---- persistent RNN kernel: 256 blocks x 512 thr (8 waves, 2/SIMD) ----
__global__ void __launch_bounds__(512, 2) rnn_persist(
    const float* __restrict__ x,   // [B_,T_]
    const float* __restrict__ U,   // [H_]
    const float* __restrict__ W,   // [H_,H_] fp32
    const float* __restrict__ bh,  // [H_]
    half_t* __restrict__ hP0,      // packed state buf 0 (1 MB)
    half_t* __restrict__ hP1,      // packed state buf 1 (1 MB)
    float* __restrict__ hf32,      // d_out h_last region (row-major fp32)
    unsigned* __restrict__ flags)
{
    const int tid  = threadIdx.x;
    const int wave = tid >> 6, lane = tid & 63;
    const int quad = lane >> 4, lq = lane & 15;
    const int id   = blockIdx.x;
    const int g    = id & 7;                      // group = XCD under id%8
    const int C    = id >> 3;                     // block-in-group 0..31
    const int m0   = g * 32;                      // group rows m0..m0+31
    const int n0   = C * 64;                      // block cols n0..n0+63

    // ---- one-time: W frags for this wave's K-range -> regs (fp16) ----
    // wave covers k in [wave*256, wave*256+256); kk = 32-wide k-subchunk
    half8 Bw[8][4];
#pragma unroll
    for (int kk = 0; kk < 8; ++kk) {
#pragma unroll
        for (int nt = 0; nt < 4; ++nt) {
            const int gn = n0 + nt * 16 + lq;
            const int k0 = wave * 256 + kk * 32 + quad * 8;
            const float4 w0 = *(const float4*)&W[(size_t)gn * H_ + k0];
            const float4 w1 = *(const float4*)&W[(size_t)gn * H_ + k0 + 4];
            const float wv[8] = {w0.x, w0.y, w0.z, w0.w, w1.x, w1.y, w1.z, w1.w};
            half8 hw;
#pragma unroll
            for (int j = 0; j < 8; ++j) hw[j] = (half_t)wv[j];
            Bw[kk][nt] = hw;
        }
    }

    // epilogue-owner role: wave w owns output tile (mtO, ntO); 2x4 = 8 tiles
    const int mtO = wave & 1, ntO = wave >> 1;
    const float uvO = U[n0 + ntO * 16 + lq];
    const float bvO = bh[n0 + ntO * 16 + lq];

    __shared__ floatx4 red[2][8][4][64];          // 8-way k-split, 64 KB
    __shared__ float Sm[32][65];                  // epilogue transpose, 8.3 KB
    __shared__ float xs[T_][32];                  // x slab transposed, 16 KB

    for (int i = tid; i < 32 * T_; i += 512) {    // one-time x staging
        const int r = i & 31, tt = i >> 5;
        xs[tt][r] = x[(size_t)(m0 + r) * T_ + tt];
    }
    __syncthreads();

    // producer mapping: thread tid == u64 index in this block's 512-u64
    // region; region layout idx = mt*256 + kc*128 + k8*32 + rlo*2 + q
    //   -> r = (tid>>8)*16 + ((tid>>1)&15)
    //      c = ((tid>>7)&1)*32 + ((tid>>5)&3)*8 + (tid&1)*4
    const int prow = (tid >> 8) * 16 + ((tid >> 1) & 15);   // local row 0..31
    const int pcol = ((tid >> 7) & 1) * 32 + ((tid >> 5) & 3) * 8 + (tid & 1) * 4;
    const size_t slab = (size_t)g * 16384;                  // u64 units (128 KB)
    const size_t pdst = slab + (size_t)C * 512 + tid;
    const size_t cbase = slab + (size_t)wave * 2048 + (size_t)lane * 2;

    // flag addresses
    unsigned* myflag_base = flags + ((size_t)g * 32 + C) * 32;   // + t*8192
    const unsigned* pollp = flags + ((size_t)g * 32 + wave * 4 + (lane & 3)) * 32;

    // ---- step 0: h1 = tanh(x*U + bh) -> packed hP1, signal slot 0 ----
    {
        const float xb = xs[0][prow];
        half4v hv;
#pragma unroll
        for (int j = 0; j < 4; ++j) {
            const int n = n0 + pcol + j;
            hv[j] = (half_t)fast_tanh(xb * U[n] + bh[n]);
        }
        __hip_atomic_store((u64*)hP1 + pdst, __builtin_bit_cast(u64, hv),
                           __ATOMIC_RELAXED, __HIP_MEMORY_SCOPE_AGENT);
    }
    __syncthreads();                              // drain all lanes' publishes
    if (tid == 0) signal_flag(myflag_base);

    // ---- steps t = 1..127 ----
    for (int t = 1; t < T_; ++t) {
        const half_t* hin = (t & 1) ? hP1 : hP0;  // h_t (packed)
        half_t* hout      = (t & 1) ? hP0 : hP1;  // h_{t+1} (packed)
        const u64* pw = (const u64*)hin + cbase;

        // wave-level poll: my 4 producers for slot t-1 (hardened: v >= 2)
        {
            const unsigned* fp = pollp + (size_t)(t - 1) * (8 * 32 * 32);
            while (true) {
                const unsigned v = __hip_atomic_load(fp, __ATOMIC_RELAXED,
                                                     __HIP_MEMORY_SCOPE_AGENT);
                if (__all(v >= 2u)) break;
                __builtin_amdgcn_s_sleep(1);
            }
            asm volatile("" ::: "memory");        // no load hoisting above poll
        }

        floatx4 acc[2][4] = {};

        u64 rl[8], rh[8];                         // ring-8 of 16B frags
        auto issue = [&](int f) {
            // f -> (c'=f>>2, mt=(f>>1)&1, kc=f&1)
            const u64* q = pw + (size_t)((f >> 2) * 512 + ((f >> 1) & 1) * 256
                                         + (f & 1) * 128);
            rl[f & 7] = __hip_atomic_load(q, __ATOMIC_RELAXED,
                                          __HIP_MEMORY_SCOPE_AGENT);
            rh[f & 7] = __hip_atomic_load(q + 1, __ATOMIC_RELAXED,
                                          __HIP_MEMORY_SCOPE_AGENT);
        };
#pragma unroll
        for (int f = 0; f < 8; ++f) issue(f);
#pragma unroll
        for (int f = 0; f < 16; ++f) {            // 16 A-frags
            const int cp = f >> 2, mt = (f >> 1) & 1, kc = f & 1;
            const int kk = cp * 2 + kc;
            u64x2 bits; bits.x = rl[f & 7]; bits.y = rh[f & 7];
            const half8 av = __builtin_bit_cast(half8, bits);
            if (f + 8 < 16) issue(f + 8);
            acc[mt][0] = __builtin_amdgcn_mfma_f32_16x16x32_f16(av, Bw[kk][0], acc[mt][0], 0, 0, 0);
            acc[mt][1] = __builtin_amdgcn_mfma_f32_16x16x32_f16(av, Bw[kk][1], acc[mt][1], 0, 0, 0);
            acc[mt][2] = __builtin_amdgcn_mfma_f32_16x16x32_f16(av, Bw[kk][2], acc[mt][2], 0, 0, 0);
            acc[mt][3] = __builtin_amdgcn_mfma_f32_16x16x32_f16(av, Bw[kk][3], acc[mt][3], 0, 0, 0);
        }

        // ---- 8-way K-split reduction ----
#pragma unroll
        for (int mt = 0; mt < 2; ++mt)
#pragma unroll
            for (int nt = 0; nt < 4; ++nt)
                red[mt][wave][nt][lane] = acc[mt][nt];
        __syncthreads();

        // owner wave: sum 8 partials, +x*U+bh, tanh -> Sm
        {
            float xr[4];
#pragma unroll
            for (int r = 0; r < 4; ++r) xr[r] = xs[t][mtO * 16 + quad * 4 + r];
            floatx4 s = red[mtO][0][ntO][lane];
#pragma unroll
            for (int ww = 1; ww < 8; ++ww) s += red[mtO][ww][ntO][lane];
#pragma unroll
            for (int r = 0; r < 4; ++r) {
                const float pre = s[r] + xr[r] * uvO + bvO;
                Sm[mtO * 16 + quad * 4 + r][ntO * 16 + lq] = fast_tanh(pre);
            }
        }
        __syncthreads();

        // publish: 1 u64 (4 halfs) per thread into the packed slab
        {
            float fv[4];
#pragma unroll
            for (int j = 0; j < 4; ++j) fv[j] = Sm[prow][pcol + j];
            half4v hv;
#pragma unroll
            for (int j = 0; j < 4; ++j) hv[j] = (half_t)fv[j];
            __hip_atomic_store((u64*)hout + pdst, __builtin_bit_cast(u64, hv),
                               __ATOMIC_RELAXED, __HIP_MEMORY_SCOPE_AGENT);
            if (t == T_ - 1) {  // final h_128 also to d_out, row-major fp32
                float* fd = hf32 + (size_t)(m0 + prow) * H_ + n0 + pcol;
                *(float4*)fd = make_float4(fv[0], fv[1], fv[2], fv[3]);
            }
        }
        if (t < T_ - 1) {
            __syncthreads();                      // drain publishes block-wide
            if (tid == 0)
                signal_flag(myflag_base + (size_t)t * (8 * 32 * 32));
        }
    }
}

// ---- output projection: out[b,c] = h[b,:] . V[c,:] + bp[c] ----
__global__ __launch_bounds__(256) void rnn_out(
    const float* __restrict__ h, const float* __restrict__ V,
    const float* __restrict__ bp, float* __restrict__ outp) {
    const int b = blockIdx.x;
    const int tid = threadIdx.x;
    float acc[C_] = {};
    for (int k = tid; k < H_; k += 256) {
        const float hv = h[(size_t)b * H_ + k];
#pragma unroll
        for (int c = 0; c < C_; ++c) acc[c] += hv * V[(size_t)c * H_ + k];
    }
#pragma unroll
    for (int c = 0; c < C_; ++c)
#pragma unroll
        for (int off = 32; off > 0; off >>= 1)
            acc[c] += __shfl_down(acc[c], off, 64);
    __shared__ float partial[4][C_];
    const int wave = tid >> 6, lane = tid & 63;
    if (lane == 0)
#pragma unroll
        for (int c = 0; c < C_; ++c) partial[wave][c] = acc[c];
    __syncthreads();
    if (tid < C_)
        outp[b * C_ + tid] = partial[0][tid] + partial[1][tid]
                           + partial[2][tid] + partial[3][tid] + bp[tid];
}

extern "C" void kernel_launch(void* const* d_in, const int* in_sizes, int n_in,
                              void* d_out, int out_size, void* d_ws, size_t ws_size,
                              hipStream_t stream) {
    const float* x  = (const float*)d_in[0];
    const float* U  = (const float*)d_in[1];
    const float* W  = (const float*)d_in[2];
    const float* V  = (const float*)d_in[3];
    const float* bh = (const float*)d_in[4];
    const float* bp = (const float*)d_in[5];

    float* out_h = (float*)d_out;                 // [B_*H_] fp32 h_last
    float* outp  = out_h + (size_t)B_ * H_;       // [B_*C_]

    half_t* hP0 = (half_t*)d_ws;                                   // 1 MB packed
    half_t* hP1 = hP0 + (size_t)B_ * H_;                           // 1 MB packed
    unsigned* flags = (unsigned*)((char*)d_ws + 2u * 1024 * 1024); // 4 MB

    hipMemsetAsync(flags, 0, FLAG_DWORDS * sizeof(unsigned), stream);

    rnn_persist<<<dim3(256), dim3(512), 0, stream>>>(
        x, U, W, bh, hP0, hP1, out_h, flags);

    rnn_out<<<dim3(B_), dim3(256), 0, stream>>>(out_h, V, bp, outp);
}

// Round 3
// 662.004 us; speedup vs baseline: 1.6221x; 1.0493x over previous
//
#include <hip/hip_runtime.h>
#include <cmath>

// VanillaRNN: B=256, T=128, D=1, H=2048, C=10
// R14: R13 sharding (8 groups x 32 blocks, W fp16 in 128 VGPRs, 64 cols x
// 2048 K per block) with the h-exchange switched from posted atomic STOREs
// to agent-scope atomic EXCHANGEs (RMW). Rationale (from R13 counters):
// FETCH_SIZE/WRITE_SIZE showed ~128 MB each = 1 MB/step/way, i.e. the
// posted sc1 stores write through the MALL without allocating and the
// first consumer read per line missed MALL -> HBM round trip on the
// critical path every step. RMWs execute AND allocate at the MALL, so
// consumer reads hit MALL; and an RMW's vmcnt only drains when its
// response returns (= committed at the coherence point), so the
// pre-signal __syncthreads now PROVES all 512 publishes are globally
// visible. That proof makes the R12 two-chained-RMW flag hardening
// redundant: tid0 issues ONE flag RMW (strictly after data commit),
// consumers poll v >= 1. Overwrite-safety transitivity unchanged: all 32
// group producers' t-1 flags are collectively polled (8 waves x 4) before
// any wave passes the pre-reduction __syncthreads.

#define B_ 256
#define T_ 128
#define H_ 2048
#define C_ 10

typedef _Float16 half_t;
typedef _Float16 half8 __attribute__((ext_vector_type(8)));
typedef _Float16 half4v __attribute__((ext_vector_type(4)));
typedef float floatx4 __attribute__((ext_vector_type(4)));
typedef unsigned long long u64;
typedef unsigned long long u64x2 __attribute__((ext_vector_type(2)));

// flag array: dword index  t*(8*32*32) + (g*32 + C)*32  (one 128B line per
// flag). t in [0,127), g in [0,8), C = producer block-in-group [0,32).
#define FLAG_DWORDS (128 * 8 * 32 * 32)   // 4 MB

__device__ __forceinline__ float fast_tanh(float v) {
    return 1.0f - 2.0f / (__expf(2.0f * v) + 1.0f);
}

// publish one u64 of packed halfs via RMW (commits+allocates at MALL; the
// returned old value is kept live so the swap cannot be demoted to a
// posted store)
__device__ __forceinline__ void publish_u64(u64* p, u64 v) {
    u64 old = __hip_atomic_exchange(p, v, __ATOMIC_RELAXED,
                                    __HIP_MEMORY_SCOPE_AGENT);
    asm volatile("" :: "v"(old));
}

// ---- persistent RNN kernel: 256 blocks x 512 thr (8 waves, 2/SIMD) ----
__global__ void __launch_bounds__(512, 2) rnn_persist(
    const float* __restrict__ x,   // [B_,T_]
    const float* __restrict__ U,   // [H_]
    const float* __restrict__ W,   // [H_,H_] fp32
    const float* __restrict__ bh,  // [H_]
    half_t* __restrict__ hP0,      // packed state buf 0 (1 MB)
    half_t* __restrict__ hP1,      // packed state buf 1 (1 MB)
    float* __restrict__ hf32,      // d_out h_last region (row-major fp32)
    unsigned* __restrict__ flags)
{
    const int tid  = threadIdx.x;
    const int wave = tid >> 6, lane = tid & 63;
    const int quad = lane >> 4, lq = lane & 15;
    const int id   = blockIdx.x;
    const int g    = id & 7;                      // group = XCD under id%8
    const int C    = id >> 3;                     // block-in-group 0..31
    const int m0   = g * 32;                      // group rows m0..m0+31
    const int n0   = C * 64;                      // block cols n0..n0+63

    // ---- one-time: W frags for this wave's K-range -> regs (fp16) ----
    // wave covers k in [wave*256, wave*256+256); kk = 32-wide k-subchunk
    half8 Bw[8][4];
#pragma unroll
    for (int kk = 0; kk < 8; ++kk) {
#pragma unroll
        for (int nt = 0; nt < 4; ++nt) {
            const int gn = n0 + nt * 16 + lq;
            const int k0 = wave * 256 + kk * 32 + quad * 8;
            const float4 w0 = *(const float4*)&W[(size_t)gn * H_ + k0];
            const float4 w1 = *(const float4*)&W[(size_t)gn * H_ + k0 + 4];
            const float wv[8] = {w0.x, w0.y, w0.z, w0.w, w1.x, w1.y, w1.z, w1.w};
            half8 hw;
#pragma unroll
            for (int j = 0; j < 8; ++j) hw[j] = (half_t)wv[j];
            Bw[kk][nt] = hw;
        }
    }

    // epilogue-owner role: wave w owns output tile (mtO, ntO); 2x4 = 8 tiles
    const int mtO = wave & 1, ntO = wave >> 1;
    const float uvO = U[n0 + ntO * 16 + lq];
    const float bvO = bh[n0 + ntO * 16 + lq];

    __shared__ floatx4 red[2][8][4][64];          // 8-way k-split, 64 KB
    __shared__ float Sm[32][65];                  // epilogue transpose, 8.3 KB
    __shared__ float xs[T_][32];                  // x slab transposed, 16 KB

    for (int i = tid; i < 32 * T_; i += 512) {    // one-time x staging
        const int r = i & 31, tt = i >> 5;
        xs[tt][r] = x[(size_t)(m0 + r) * T_ + tt];
    }
    __syncthreads();

    // producer mapping: thread tid == u64 index in this block's 512-u64
    // region; region layout idx = mt*256 + kc*128 + k8*32 + rlo*2 + q
    //   -> r = (tid>>8)*16 + ((tid>>1)&15)
    //      c = ((tid>>7)&1)*32 + ((tid>>5)&3)*8 + (tid&1)*4
    const int prow = (tid >> 8) * 16 + ((tid >> 1) & 15);   // local row 0..31
    const int pcol = ((tid >> 7) & 1) * 32 + ((tid >> 5) & 3) * 8 + (tid & 1) * 4;
    const size_t slab = (size_t)g * 16384;                  // u64 units (128 KB)
    const size_t pdst = slab + (size_t)C * 512 + tid;
    const size_t cbase = slab + (size_t)wave * 2048 + (size_t)lane * 2;

    // flag addresses
    unsigned* myflag_base = flags + ((size_t)g * 32 + C) * 32;   // + t*8192
    const unsigned* pollp = flags + ((size_t)g * 32 + wave * 4 + (lane & 3)) * 32;

    // ---- step 0: h1 = tanh(x*U + bh) -> packed hP1, signal slot 0 ----
    {
        const float xb = xs[0][prow];
        half4v hv;
#pragma unroll
        for (int j = 0; j < 4; ++j) {
            const int n = n0 + pcol + j;
            hv[j] = (half_t)fast_tanh(xb * U[n] + bh[n]);
        }
        publish_u64((u64*)hP1 + pdst, __builtin_bit_cast(u64, hv));
    }
    __syncthreads();          // drains vmcnt: all exchanges committed at MALL
    if (tid == 0)
        __hip_atomic_fetch_add(myflag_base, 1u, __ATOMIC_RELAXED,
                               __HIP_MEMORY_SCOPE_AGENT);

    // ---- steps t = 1..127 ----
    for (int t = 1; t < T_; ++t) {
        const half_t* hin = (t & 1) ? hP1 : hP0;  // h_t (packed)
        half_t* hout      = (t & 1) ? hP0 : hP1;  // h_{t+1} (packed)
        const u64* pw = (const u64*)hin + cbase;

        // wave-level poll: my 4 producers for slot t-1 (v >= 1; the flag RMW
        // is issued only after all of that producer's data RMWs committed)
        {
            const unsigned* fp = pollp + (size_t)(t - 1) * (8 * 32 * 32);
            while (true) {
                const unsigned v = __hip_atomic_load(fp, __ATOMIC_RELAXED,
                                                     __HIP_MEMORY_SCOPE_AGENT);
                if (__all(v >= 1u)) break;
                __builtin_amdgcn_s_sleep(1);
            }
            asm volatile("" ::: "memory");        // no load hoisting above poll
        }

        floatx4 acc[2][4] = {};

        u64 rl[8], rh[8];                         // ring-8 of 16B frags
        auto issue = [&](int f) {
            // f -> (c'=f>>2, mt=(f>>1)&1, kc=f&1)
            const u64* q = pw + (size_t)((f >> 2) * 512 + ((f >> 1) & 1) * 256
                                         + (f & 1) * 128);
            rl[f & 7] = __hip_atomic_load(q, __ATOMIC_RELAXED,
                                          __HIP_MEMORY_SCOPE_AGENT);
            rh[f & 7] = __hip_atomic_load(q + 1, __ATOMIC_RELAXED,
                                          __HIP_MEMORY_SCOPE_AGENT);
        };
#pragma unroll
        for (int f = 0; f < 8; ++f) issue(f);
#pragma unroll
        for (int f = 0; f < 16; ++f) {            // 16 A-frags
            const int cp = f >> 2, mt = (f >> 1) & 1, kc = f & 1;
            const int kk = cp * 2 + kc;
            u64x2 bits; bits.x = rl[f & 7]; bits.y = rh[f & 7];
            const half8 av = __builtin_bit_cast(half8, bits);
            if (f + 8 < 16) issue(f + 8);
            acc[mt][0] = __builtin_amdgcn_mfma_f32_16x16x32_f16(av, Bw[kk][0], acc[mt][0], 0, 0, 0);
            acc[mt][1] = __builtin_amdgcn_mfma_f32_16x16x32_f16(av, Bw[kk][1], acc[mt][1], 0, 0, 0);
            acc[mt][2] = __builtin_amdgcn_mfma_f32_16x16x32_f16(av, Bw[kk][2], acc[mt][2], 0, 0, 0);
            acc[mt][3] = __builtin_amdgcn_mfma_f32_16x16x32_f16(av, Bw[kk][3], acc[mt][3], 0, 0, 0);
        }

        // ---- 8-way K-split reduction ----
#pragma unroll
        for (int mt = 0; mt < 2; ++mt)
#pragma unroll
            for (int nt = 0; nt < 4; ++nt)
                red[mt][wave][nt][lane] = acc[mt][nt];
        __syncthreads();

        // owner wave: sum 8 partials, +x*U+bh, tanh -> Sm
        {
            float xr[4];
#pragma unroll
            for (int r = 0; r < 4; ++r) xr[r] = xs[t][mtO * 16 + quad * 4 + r];
            floatx4 s = red[mtO][0][ntO][lane];
#pragma unroll
            for (int ww = 1; ww < 8; ++ww) s += red[mtO][ww][ntO][lane];
#pragma unroll
            for (int r = 0; r < 4; ++r) {
                const float pre = s[r] + xr[r] * uvO + bvO;
                Sm[mtO * 16 + quad * 4 + r][ntO * 16 + lq] = fast_tanh(pre);
            }
        }
        __syncthreads();

        // publish: 1 u64 (4 halfs) per thread into the packed slab (RMW)
        {
            float fv[4];
#pragma unroll
            for (int j = 0; j < 4; ++j) fv[j] = Sm[prow][pcol + j];
            half4v hv;
#pragma unroll
            for (int j = 0; j < 4; ++j) hv[j] = (half_t)fv[j];
            publish_u64((u64*)hout + pdst, __builtin_bit_cast(u64, hv));
            if (t == T_ - 1) {  // final h_128 also to d_out, row-major fp32
                float* fd = hf32 + (size_t)(m0 + prow) * H_ + n0 + pcol;
                *(float4*)fd = make_float4(fv[0], fv[1], fv[2], fv[3]);
            }
        }
        if (t < T_ - 1) {
            __syncthreads();  // drains vmcnt: all exchanges committed at MALL
            if (tid == 0)
                __hip_atomic_fetch_add(
                    myflag_base + (size_t)t * (8 * 32 * 32), 1u,
                    __ATOMIC_RELAXED, __HIP_MEMORY_SCOPE_AGENT);
        }
    }
}

// ---- output projection: out[b,c] = h[b,:] . V[c,:] + bp[c] ----
__global__ __launch_bounds__(256) void rnn_out(
    const float* __restrict__ h, const float* __restrict__ V,
    const float* __restrict__ bp, float* __restrict__ outp) {
    const int b = blockIdx.x;
    const int tid = threadIdx.x;
    float acc[C_] = {};
    for (int k = tid; k < H_; k += 256) {
        const float hv = h[(size_t)b * H_ + k];
#pragma unroll
        for (int c = 0; c < C_; ++c) acc[c] += hv * V[(size_t)c * H_ + k];
    }
#pragma unroll
    for (int c = 0; c < C_; ++c)
#pragma unroll
        for (int off = 32; off > 0; off >>= 1)
            acc[c] += __shfl_down(acc[c], off, 64);
    __shared__ float partial[4][C_];
    const int wave = tid >> 6, lane = tid & 63;
    if (lane == 0)
#pragma unroll
        for (int c = 0; c < C_; ++c) partial[wave][c] = acc[c];
    __syncthreads();
    if (tid < C_)
        outp[b * C_ + tid] = partial[0][tid] + partial[1][tid]
                           + partial[2][tid] + partial[3][tid] + bp[tid];
}

extern "C" void kernel_launch(void* const* d_in, const int* in_sizes, int n_in,
                              void* d_out, int out_size, void* d_ws, size_t ws_size,
                              hipStream_t stream) {
    const float* x  = (const float*)d_in[0];
    const float* U  = (const float*)d_in[1];
    const float* W  = (const float*)d_in[2];
    const float* V  = (const float*)d_in[3];
    const float* bh = (const float*)d_in[4];
    const float* bp = (const float*)d_in[5];

    float* out_h = (float*)d_out;                 // [B_*H_] fp32 h_last
    float* outp  = out_h + (size_t)B_ * H_;       // [B_*C_]

    half_t* hP0 = (half_t*)d_ws;                                   // 1 MB packed
    half_t* hP1 = hP0 + (size_t)B_ * H_;                           // 1 MB packed
    unsigned* flags = (unsigned*)((char*)d_ws + 2u * 1024 * 1024); // 4 MB

    hipMemsetAsync(flags, 0, FLAG_DWORDS * sizeof(unsigned), stream);

    rnn_persist<<<dim3(256), dim3(512), 0, stream>>>(
        x, U, W, bh, hP0, hP1, out_h, flags);

    rnn_out<<<dim3(B_), dim3(256), 0, stream>>>(out_h, V, bp, outp);
}